// Round 7
// baseline (730.866 us; speedup 1.0000x reference)
//
#include <hip/hip_runtime.h>

typedef unsigned short u16;
typedef u16 u16x8 __attribute__((ext_vector_type(8)));
typedef __bf16 bf16x8 __attribute__((ext_vector_type(8)));
typedef float f32x4 __attribute__((ext_vector_type(4)));

#define NE 8
#define SA 72  // LDS row stride in u16

// ---- helpers ----
__device__ __forceinline__ unsigned pk2(float a, float b) {
  unsigned ua = __builtin_bit_cast(unsigned, a) + 0x8000u;
  unsigned ub = __builtin_bit_cast(unsigned, b) + 0x8000u;
  return __builtin_amdgcn_perm(ub, ua, 0x07060302);
}
__device__ __forceinline__ u16 f2bf(float f) {
  return (u16)((__builtin_bit_cast(unsigned, f) + 0x8000u) >> 16);
}
__device__ __forceinline__ uint4 pk8(f32x4 a, f32x4 b) {
  return make_uint4(pk2(a[0], a[1]), pk2(a[2], a[3]),
                    pk2(b[0], b[1]), pk2(b[2], b[3]));
}
__device__ __forceinline__ bf16x8 ldfrag(const u16* p) {
  union { u16x8 u; bf16x8 b; } x;
  x.u = *(const u16x8*)p;
  return x.b;
}

// ---- routing ----
__global__ __launch_bounds__(64) void routing_kernel(
    const float* __restrict__ x, const float* __restrict__ gw,
    const float* __restrict__ segw, int* __restrict__ counts,
    int* __restrict__ ptok, float* __restrict__ pw, float* __restrict__ sgate) {
  int t = blockIdx.x;
  int lane = threadIdx.x;
  const float* xr = x + (size_t)t * 2048;
  float s[NE];
#pragma unroll
  for (int e = 0; e < NE; e++) s[e] = 0.f;
  float sg = 0.f;
  for (int c = lane; c < 2048; c += 64) {
    float xv = xr[c];
#pragma unroll
    for (int e = 0; e < NE; e++) s[e] += xv * gw[e * 2048 + c];
    sg += xv * segw[c];
  }
#pragma unroll
  for (int off = 32; off > 0; off >>= 1) {
#pragma unroll
    for (int e = 0; e < NE; e++) s[e] += __shfl_down(s[e], off);
    sg += __shfl_down(sg, off);
  }
  if (lane == 0) {
    int i0 = 0;
#pragma unroll
    for (int e = 1; e < NE; e++) if (s[e] > s[i0]) i0 = e;
    int i1 = (i0 == 0) ? 1 : 0;
#pragma unroll
    for (int e = 0; e < NE; e++) if (e != i0 && s[e] > s[i1]) i1 = e;
    float r = __expf(s[i1] - s[i0]);
    float w0 = 1.f / (1.f + r);
    float w1 = 1.f - w0;
    int s0 = atomicAdd(&counts[i0], 1);
    ptok[(i0 << 9) + s0] = t; pw[(i0 << 9) + s0] = w0;
    int s1 = atomicAdd(&counts[i1], 1);
    ptok[(i1 << 9) + s1] = t; pw[(i1 << 9) + s1] = w1;
    sgate[t] = 1.f / (1.f + __expf(-sg));
  }
}

// ---- prep: x fp32 -> bf16 once ----
__global__ __launch_bounds__(256) void prep_kernel(
    const float* __restrict__ x, u16* __restrict__ xb) {
  int i = (blockIdx.x * 256 + threadIdx.x) * 32;
  const float* p = x + i;
  u16* o = xb + i;
#pragma unroll
  for (int s = 0; s < 4; s++) {
    f32x4 a = *(const f32x4*)(p + s * 8);
    f32x4 b = *(const f32x4*)(p + s * 8 + 4);
    *(uint4*)(o + s * 8) = pk8(a, b);
  }
}

// ---- gateup: M=128 x (16 gate + 16 up), BK=64, full K, silu fused ----
// Output in BLOCKED layout: hbufB[e][j][slot(512)][16], hsB[j][slot(512)][16].
// NOTE: plain __launch_bounds__(256) — the (256,4) min-waves variant made the
// backend cut VGPRs to 36 and spill prefetch state to scratch (WRITE_SIZE
// 288 MB of spill traffic, 10k cyc/iter). Occupancy comes from the grid.
__global__ __launch_bounds__(256) void gateup_kernel(
    const u16* __restrict__ xb, const float* __restrict__ Wg,
    const float* __restrict__ Wu, const float* __restrict__ SWg,
    const float* __restrict__ SWu, u16* __restrict__ hbufB,
    u16* __restrict__ hsB, const int* __restrict__ ptok,
    const int* __restrict__ counts) {
  __shared__ u16 As[128 * SA];
  __shared__ u16 Bs[32 * SA];

  int b = blockIdx.x;
  int t = threadIdx.x;
  int is_ex = (b < 2048);
  int e = 0, j, mt, cnt;
  const float *gW, *uW;
  u16* obase;
  if (is_ex) {
    e = b & 7; j = (b >> 3) & 63; mt = b >> 9;
    cnt = counts[e];
    if (mt * 128 >= cnt) return;
    gW = Wg + (size_t)(e * 1024 + j * 16) * 2048;
    uW = Wu + (size_t)(e * 1024 + j * 16) * 2048;
    obase = hbufB + ((size_t)(e * 64 + j) * 512) * 16;
  } else {
    int bs = b - 2048; j = bs & 127; mt = bs >> 7; cnt = 512;
    gW = SWg + (size_t)(j * 16) * 2048;
    uW = SWu + (size_t)(j * 16) * 2048;
    obase = hsB + ((size_t)j * 512) * 16;
  }

  // A staging: arow 0..127, half = 32 bf16 (64 B/thread/iter)
  int arow = t >> 1, ahalf = t & 1;
  int aslot = mt * 128 + arow;
  int tok = is_ex ? ((aslot < cnt) ? ptok[(e << 9) + aslot] : 0) : aslot;
  const u16* ap = xb + (size_t)tok * 2048 + ahalf * 32;

  // B staging: wrow 0..31 (0-15 gate, 16-31 up), 8 fp32/thread
  int wrow = t >> 3, wseg = t & 7;
  const float* wp = ((wrow < 16) ? (gW + (size_t)wrow * 2048)
                                 : (uW + (size_t)(wrow - 16) * 2048)) + wseg * 8;

  int lane = t & 63, wv = t >> 6;
  int quad = lane >> 4, l16 = lane & 15;

  f32x4 accg[2] = {}, accu[2] = {};
  uint4 apre[4]; f32x4 bpre[2];
#pragma unroll
  for (int s = 0; s < 4; s++) apre[s] = *(const uint4*)(ap + s * 8);
  bpre[0] = *(const f32x4*)(wp);
  bpre[1] = *(const f32x4*)(wp + 4);

  int awr = arow * SA + ahalf * 32;
  int bwr = wrow * SA + wseg * 8;

  const int NIT = 32;  // K=2048 / 64
  for (int kt = 0; kt < NIT; kt++) {
    __syncthreads();
#pragma unroll
    for (int s = 0; s < 4; s++) *(uint4*)&As[awr + s * 8] = apre[s];
    *(uint4*)&Bs[bwr] = pk8(bpre[0], bpre[1]);
    __syncthreads();
    if (kt + 1 < NIT) {
      const u16* a0 = ap + (kt + 1) * 64;
      const float* w0 = wp + (kt + 1) * 64;
#pragma unroll
      for (int s = 0; s < 4; s++) apre[s] = *(const uint4*)(a0 + s * 8);
      bpre[0] = *(const f32x4*)(w0);
      bpre[1] = *(const f32x4*)(w0 + 4);
    }
#pragma unroll
    for (int k2 = 0; k2 < 2; k2++) {
      bf16x8 af0 = ldfrag(&As[(wv * 32 + l16) * SA + k2 * 32 + quad * 8]);
      bf16x8 af1 = ldfrag(&As[(wv * 32 + 16 + l16) * SA + k2 * 32 + quad * 8]);
      bf16x8 bg = ldfrag(&Bs[l16 * SA + k2 * 32 + quad * 8]);
      bf16x8 bu = ldfrag(&Bs[(16 + l16) * SA + k2 * 32 + quad * 8]);
      accg[0] = __builtin_amdgcn_mfma_f32_16x16x32_bf16(af0, bg, accg[0], 0, 0, 0);
      accg[1] = __builtin_amdgcn_mfma_f32_16x16x32_bf16(af1, bg, accg[1], 0, 0, 0);
      accu[0] = __builtin_amdgcn_mfma_f32_16x16x32_bf16(af0, bu, accu[0], 0, 0, 0);
      accu[1] = __builtin_amdgcn_mfma_f32_16x16x32_bf16(af1, bu, accu[1], 0, 0, 0);
    }
  }

  // epilogue: h = silu(g)*u -> blocked layout (contiguous per block)
#pragma unroll
  for (int i = 0; i < 2; i++)
#pragma unroll
    for (int g = 0; g < 4; g++) {
      int rloc = wv * 32 + i * 16 + quad * 4 + g;
      int slot = mt * 128 + rloc;
      if (slot < cnt) {
        float gv = accg[i][g], uv = accu[i][g];
        float h = gv / (1.f + __expf(-gv)) * uv;
        obase[(size_t)slot * 16 + l16] = f2bf(h);
      }
    }
}

// ---- down shared: out[row] = sgate[row] * (hs @ SWd^T)  (plain store) ----
// M=128 x N=16, full K=2048. Grid 512: nt = b&127, mt = b>>7.
__global__ __launch_bounds__(256) void down_shared_kernel(
    const u16* __restrict__ hsB, const float* __restrict__ SWd,
    float* __restrict__ out, const float* __restrict__ sgate) {
  __shared__ u16 As[128 * SA];
  __shared__ u16 Bs[16 * SA];

  int b = blockIdx.x;
  int t = threadIdx.x;
  int nt = b & 127, mt = b >> 7;

  int arow = t >> 1, ahalf = t & 1;
  int slot = mt * 128 + arow;
  const u16* ab = hsB + (size_t)slot * 16;  // + j*8192 + c

  int wrow = t >> 4, wseg = t & 15;
  const float* wp = SWd + (size_t)(nt * 16 + wrow) * 2048 + wseg * 4;

  int lane = t & 63, wv = t >> 6;
  int quad = lane >> 4, l16 = lane & 15;

  f32x4 acc[2] = {};
  uint4 apre[4]; f32x4 bpre;
  {
    int j0 = ahalf * 2;
    apre[0] = *(const uint4*)(ab + j0 * 8192);
    apre[1] = *(const uint4*)(ab + j0 * 8192 + 8);
    apre[2] = *(const uint4*)(ab + (j0 + 1) * 8192);
    apre[3] = *(const uint4*)(ab + (j0 + 1) * 8192 + 8);
    bpre = *(const f32x4*)(wp);
  }

  int awr = arow * SA + ahalf * 32;
  int bwr = wrow * SA + wseg * 4;

  const int NIT = 32;  // K=2048/64
  for (int kt = 0; kt < NIT; kt++) {
    __syncthreads();
#pragma unroll
    for (int s = 0; s < 4; s++) *(uint4*)&As[awr + s * 8] = apre[s];
    *(uint2*)&Bs[bwr] = make_uint2(pk2(bpre[0], bpre[1]), pk2(bpre[2], bpre[3]));
    __syncthreads();
    if (kt + 1 < NIT) {
      int j0 = (kt + 1) * 4 + ahalf * 2;
      apre[0] = *(const uint4*)(ab + j0 * 8192);
      apre[1] = *(const uint4*)(ab + j0 * 8192 + 8);
      apre[2] = *(const uint4*)(ab + (j0 + 1) * 8192);
      apre[3] = *(const uint4*)(ab + (j0 + 1) * 8192 + 8);
      bpre = *(const f32x4*)(wp + (kt + 1) * 64);
    }
#pragma unroll
    for (int k2 = 0; k2 < 2; k2++) {
      bf16x8 af0 = ldfrag(&As[(wv * 32 + l16) * SA + k2 * 32 + quad * 8]);
      bf16x8 af1 = ldfrag(&As[(wv * 32 + 16 + l16) * SA + k2 * 32 + quad * 8]);
      bf16x8 bb = ldfrag(&Bs[l16 * SA + k2 * 32 + quad * 8]);
      acc[0] = __builtin_amdgcn_mfma_f32_16x16x32_bf16(af0, bb, acc[0], 0, 0, 0);
      acc[1] = __builtin_amdgcn_mfma_f32_16x16x32_bf16(af1, bb, acc[1], 0, 0, 0);
    }
  }

#pragma unroll
  for (int i = 0; i < 2; i++)
#pragma unroll
    for (int g = 0; g < 4; g++) {
      int row = mt * 128 + wv * 32 + i * 16 + quad * 4 + g;
      out[(size_t)row * 2048 + nt * 16 + l16] = sgate[row] * acc[i][g];
    }
}

// ---- down expert: out[tok] += pw * (hbuf_e @ Wd_e^T)  (atomicAdd) ----
// M=128 x N=32, K=1024. Grid 2048: e=b&7, nt=(b>>3)&63, mt=b>>9.
__global__ __launch_bounds__(256) void down_expert_kernel(
    const u16* __restrict__ hbufB, const float* __restrict__ Wd,
    float* __restrict__ out, const int* __restrict__ ptok,
    const float* __restrict__ pw, const int* __restrict__ counts) {
  __shared__ u16 As[128 * SA];
  __shared__ u16 Bs[32 * SA];

  int b = blockIdx.x;
  int t = threadIdx.x;
  int e = b & 7, nt = (b >> 3) & 63, mt = b >> 9;
  int cnt = counts[e];
  if (mt * 128 >= cnt) return;

  int arow = t >> 1, ahalf = t & 1;
  int slot = mt * 128 + arow;
  const u16* ab = hbufB + ((size_t)e * 32768 + slot) * 16;  // + j*8192 + c

  int wrow = t >> 3, wseg = t & 7;
  const float* wp = Wd + (size_t)(e * 2048 + nt * 32 + wrow) * 1024 + wseg * 8;

  int lane = t & 63, wv = t >> 6;
  int quad = lane >> 4, l16 = lane & 15;

  f32x4 acc[2][2] = {};
  uint4 apre[4]; f32x4 bpre[2];
  {
    int j0 = ahalf * 2;
    apre[0] = *(const uint4*)(ab + j0 * 8192);
    apre[1] = *(const uint4*)(ab + j0 * 8192 + 8);
    apre[2] = *(const uint4*)(ab + (j0 + 1) * 8192);
    apre[3] = *(const uint4*)(ab + (j0 + 1) * 8192 + 8);
    bpre[0] = *(const f32x4*)(wp);
    bpre[1] = *(const f32x4*)(wp + 4);
  }

  int awr = arow * SA + ahalf * 32;
  int bwr = wrow * SA + wseg * 8;

  const int NIT = 16;  // K=1024/64
  for (int kt = 0; kt < NIT; kt++) {
    __syncthreads();
#pragma unroll
    for (int s = 0; s < 4; s++) *(uint4*)&As[awr + s * 8] = apre[s];
    *(uint4*)&Bs[bwr] = pk8(bpre[0], bpre[1]);
    __syncthreads();
    if (kt + 1 < NIT) {
      int j0 = (kt + 1) * 4 + ahalf * 2;
      apre[0] = *(const uint4*)(ab + j0 * 8192);
      apre[1] = *(const uint4*)(ab + j0 * 8192 + 8);
      apre[2] = *(const uint4*)(ab + (j0 + 1) * 8192);
      apre[3] = *(const uint4*)(ab + (j0 + 1) * 8192 + 8);
      bpre[0] = *(const f32x4*)(wp + (kt + 1) * 64);
      bpre[1] = *(const f32x4*)(wp + (kt + 1) * 64 + 4);
    }
#pragma unroll
    for (int k2 = 0; k2 < 2; k2++) {
      bf16x8 af0 = ldfrag(&As[(wv * 32 + l16) * SA + k2 * 32 + quad * 8]);
      bf16x8 af1 = ldfrag(&As[(wv * 32 + 16 + l16) * SA + k2 * 32 + quad * 8]);
      bf16x8 b0 = ldfrag(&Bs[l16 * SA + k2 * 32 + quad * 8]);
      bf16x8 b1 = ldfrag(&Bs[(16 + l16) * SA + k2 * 32 + quad * 8]);
      acc[0][0] = __builtin_amdgcn_mfma_f32_16x16x32_bf16(af0, b0, acc[0][0], 0, 0, 0);
      acc[0][1] = __builtin_amdgcn_mfma_f32_16x16x32_bf16(af0, b1, acc[0][1], 0, 0, 0);
      acc[1][0] = __builtin_amdgcn_mfma_f32_16x16x32_bf16(af1, b0, acc[1][0], 0, 0, 0);
      acc[1][1] = __builtin_amdgcn_mfma_f32_16x16x32_bf16(af1, b1, acc[1][1], 0, 0, 0);
    }
  }

#pragma unroll
  for (int i = 0; i < 2; i++)
#pragma unroll
    for (int jf = 0; jf < 2; jf++)
#pragma unroll
      for (int g = 0; g < 4; g++) {
        int sl = mt * 128 + wv * 32 + i * 16 + quad * 4 + g;
        if (sl < cnt) {
          int tok = ptok[(e << 9) + sl];
          int col = nt * 32 + jf * 16 + l16;
          atomicAdd(&out[(size_t)tok * 2048 + col], pw[(e << 9) + sl] * acc[i][jf][g]);
        }
      }
}

extern "C" void kernel_launch(void* const* d_in, const int* in_sizes, int n_in,
                              void* d_out, int out_size, void* d_ws, size_t ws_size,
                              hipStream_t stream) {
  const float* x = (const float*)d_in[0];
  const float* gate_w = (const float*)d_in[1];
  const float* w_gate = (const float*)d_in[2];
  const float* w_up = (const float*)d_in[3];
  const float* w_down = (const float*)d_in[4];
  const float* sh_gate = (const float*)d_in[5];
  const float* sh_up = (const float*)d_in[6];
  const float* sh_down = (const float*)d_in[7];
  const float* se_gate_w = (const float*)d_in[8];
  float* out = (float*)d_out;

  char* ws = (char*)d_ws;
  int* counts = (int*)(ws + 0);                       // 32 B
  int* ptok = (int*)(ws + 1024);                      // 16 KB
  float* pw = (float*)(ws + 1024 + 16384);            // 16 KB
  float* sg = (float*)(ws + 1024 + 32768);            // 2 KB
  u16* xb = (u16*)(ws + 65536);                       // 2 MB
  u16* hbufB = (u16*)(ws + 65536 + (2u << 20));       // 8 MB
  u16* hsB = (u16*)(ws + 65536 + (10u << 20));        // 2 MB

  hipMemsetAsync(counts, 0, 32, stream);
  routing_kernel<<<512, 64, 0, stream>>>(x, gate_w, se_gate_w, counts, ptok, pw, sg);
  prep_kernel<<<128, 256, 0, stream>>>(x, xb);
  // gateup: expert 8e*64j*4mt = 2048 (live ~512) + shared 128j*4mt = 512
  gateup_kernel<<<2560, 256, 0, stream>>>(xb, w_gate, w_up, sh_gate, sh_up,
                                          hbufB, hsB, ptok, counts);
  // shared down first (plain store covers every out element) ...
  down_shared_kernel<<<512, 256, 0, stream>>>(hsB, sh_down, out, sg);
  // ... then expert down atomicAdds on top
  down_expert_kernel<<<2048, 256, 0, stream>>>(hbufB, w_down, out, ptok, pw, counts);
}

// Round 8
// 396.439 us; speedup vs baseline: 1.8436x; 1.8436x over previous
//
#include <hip/hip_runtime.h>

typedef unsigned short u16;
typedef u16 u16x8 __attribute__((ext_vector_type(8)));
typedef __bf16 bf16x8 __attribute__((ext_vector_type(8)));
typedef float f32x4 __attribute__((ext_vector_type(4)));

#define NE 8

// ---- helpers ----
__device__ __forceinline__ unsigned pk2(float a, float b) {
  unsigned ua = __builtin_bit_cast(unsigned, a) + 0x8000u;
  unsigned ub = __builtin_bit_cast(unsigned, b) + 0x8000u;
  return __builtin_amdgcn_perm(ub, ua, 0x07060302);
}
__device__ __forceinline__ u16 f2bf(float f) {
  return (u16)((__builtin_bit_cast(unsigned, f) + 0x8000u) >> 16);
}
__device__ __forceinline__ uint4 pk8(f32x4 a, f32x4 b) {
  return make_uint4(pk2(a[0], a[1]), pk2(a[2], a[3]),
                    pk2(b[0], b[1]), pk2(b[2], b[3]));
}
__device__ __forceinline__ bf16x8 ldfrag(const u16* p) {
  union { u16x8 u; bf16x8 b; } x;
  x.u = *(const u16x8*)p;
  return x.b;
}
// load 8 fp32 from LDS, convert -> bf16x8 fragment
__device__ __forceinline__ bf16x8 cvt8(const float* p) {
  f32x4 lo = *(const f32x4*)p;
  f32x4 hi = *(const f32x4*)(p + 4);
  union { uint4 u; bf16x8 b; } x;
  x.u = pk8(lo, hi);
  return x.b;
}
// async global->LDS, 16 B/lane: HW writes lane l at (uniform lds base) + l*16
__device__ __forceinline__ void gld16(const void* g, void* l) {
  __builtin_amdgcn_global_load_lds(
      (const __attribute__((address_space(1))) unsigned int*)g,
      (__attribute__((address_space(3))) unsigned int*)l, 16, 0, 0);
}

// ---- routing ----
__global__ __launch_bounds__(64) void routing_kernel(
    const float* __restrict__ x, const float* __restrict__ gw,
    const float* __restrict__ segw, int* __restrict__ counts,
    int* __restrict__ ptok, float* __restrict__ pw, float* __restrict__ sgate) {
  int t = blockIdx.x;
  int lane = threadIdx.x;
  const float* xr = x + (size_t)t * 2048;
  float s[NE];
#pragma unroll
  for (int e = 0; e < NE; e++) s[e] = 0.f;
  float sg = 0.f;
  for (int c = lane; c < 2048; c += 64) {
    float xv = xr[c];
#pragma unroll
    for (int e = 0; e < NE; e++) s[e] += xv * gw[e * 2048 + c];
    sg += xv * segw[c];
  }
#pragma unroll
  for (int off = 32; off > 0; off >>= 1) {
#pragma unroll
    for (int e = 0; e < NE; e++) s[e] += __shfl_down(s[e], off);
    sg += __shfl_down(sg, off);
  }
  if (lane == 0) {
    int i0 = 0;
#pragma unroll
    for (int e = 1; e < NE; e++) if (s[e] > s[i0]) i0 = e;
    int i1 = (i0 == 0) ? 1 : 0;
#pragma unroll
    for (int e = 0; e < NE; e++) if (e != i0 && s[e] > s[i1]) i1 = e;
    float r = __expf(s[i1] - s[i0]);
    float w0 = 1.f / (1.f + r);
    float w1 = 1.f - w0;
    int s0 = atomicAdd(&counts[i0], 1);
    ptok[(i0 << 9) + s0] = t; pw[(i0 << 9) + s0] = w0;
    int s1 = atomicAdd(&counts[i1], 1);
    ptok[(i1 << 9) + s1] = t; pw[(i1 << 9) + s1] = w1;
    sgate[t] = 1.f / (1.f + __expf(-sg));
  }
}

// ---- prep: x fp32 -> bf16 once ----
__global__ __launch_bounds__(256) void prep_kernel(
    const float* __restrict__ x, u16* __restrict__ xb) {
  int i = (blockIdx.x * 256 + threadIdx.x) * 32;
  const float* p = x + i;
  u16* o = xb + i;
#pragma unroll
  for (int s = 0; s < 4; s++) {
    f32x4 a = *(const f32x4*)(p + s * 8);
    f32x4 b = *(const f32x4*)(p + s * 8 + 4);
    *(uint4*)(o + s * 8) = pk8(a, b);
  }
}

// ---- gateup: M=128 x (16 gate + 16 up), BK=64, full K=2048, silu fused ----
// NO cross-barrier register state: A via global_load_lds (bf16), B weights via
// global_load_lds as fp32 + in-register convert at fragment read. (R5-R7's
// register prefetch was spilled to scratch by the compiler: 288-554 MB of
// WRITE_SIZE spill traffic. This structure has nothing to spill.)
__global__ __launch_bounds__(256) void gateup_kernel(
    const u16* __restrict__ xb, const float* __restrict__ Wg,
    const float* __restrict__ Wu, const float* __restrict__ SWg,
    const float* __restrict__ SWu, u16* __restrict__ hbufB,
    u16* __restrict__ hsB, const int* __restrict__ ptok,
    const int* __restrict__ counts) {
  __shared__ __align__(16) u16 As[128 * 64];    // 16 KB, dense row-major
  __shared__ __align__(16) float Bsf[32 * 64];  // 8 KB fp32 (16 gate + 16 up)

  int b = blockIdx.x;
  int t = threadIdx.x;
  int is_ex = (b < 2048);
  int e = 0, j, mt, cnt;
  const float *gW, *uW;
  u16* obase;
  if (is_ex) {
    e = b & 7; j = (b >> 3) & 63; mt = b >> 9;
    cnt = counts[e];
    if (mt * 128 >= cnt) return;
    gW = Wg + (size_t)(e * 1024 + j * 16) * 2048;
    uW = Wu + (size_t)(e * 1024 + j * 16) * 2048;
    obase = hbufB + (size_t)(e * 64 + j) * 8192;
  } else {
    // shared: same-j blocks pinned to one XCD (b%8) so weights fetch once
    int bs = b - 2048;
    int xcd = bs & 7; mt = (bs >> 3) & 3; j = (bs >> 5) * 8 + xcd; cnt = 512;
    gW = SWg + (size_t)(j * 16) * 2048;
    uW = SWu + (size_t)(j * 16) * 2048;
    obase = hsB + (size_t)j * 8192;
  }

  int lane = t & 63, wv = t >> 6;
  int quad = lane >> 4, l16 = lane & 15;

  // A staging: 16 chunks of 8 rows x 128 B; wave wv does chunks 4wv..4wv+3.
  // lane l -> row 8c + (l>>3), 16-B seg (l&7).  (per-lane gather via ptok)
  const u16* aptr[4];
  u16* alds[4];
#pragma unroll
  for (int i = 0; i < 4; i++) {
    int c = 4 * wv + i;
    int row = 8 * c + (lane >> 3);
    int slot = mt * 128 + row;
    int tok = is_ex ? ((slot < cnt) ? ptok[(e << 9) + slot] : 0) : slot;
    aptr[i] = xb + (size_t)tok * 2048 + (lane & 7) * 8;
    alds[i] = &As[c * 512];
  }
  // B staging: 8 chunks of 4 rows x 256 B; wave wv does chunks 2wv, 2wv+1.
  // rows 0-15 = gate, 16-31 = up. lane l -> row 4c + (l>>4), seg (l&15).
  const float* bptr[2];
  float* blds[2];
#pragma unroll
  for (int i = 0; i < 2; i++) {
    int c = 2 * wv + i;
    int rloc = 4 * c + (lane >> 4);
    const float* base = (rloc < 16) ? (gW + (size_t)rloc * 2048)
                                    : (uW + (size_t)(rloc - 16) * 2048);
    bptr[i] = base + (lane & 15) * 4;
    blds[i] = &Bsf[c * 256];
  }

  f32x4 accg[2] = {}, accu[2] = {};

  for (int kt = 0; kt < 32; kt++) {
    __syncthreads();
#pragma unroll
    for (int i = 0; i < 4; i++) gld16(aptr[i] + kt * 64, alds[i]);
#pragma unroll
    for (int i = 0; i < 2; i++) gld16(bptr[i] + kt * 64, blds[i]);
    __syncthreads();  // vmcnt(0) drain -> tile visible
#pragma unroll
    for (int k2 = 0; k2 < 2; k2++) {
      bf16x8 af0 = ldfrag(&As[(wv * 32 + l16) * 64 + k2 * 32 + quad * 8]);
      bf16x8 af1 = ldfrag(&As[(wv * 32 + 16 + l16) * 64 + k2 * 32 + quad * 8]);
      bf16x8 bg = cvt8(&Bsf[l16 * 64 + k2 * 32 + quad * 8]);
      bf16x8 bu = cvt8(&Bsf[(16 + l16) * 64 + k2 * 32 + quad * 8]);
      accg[0] = __builtin_amdgcn_mfma_f32_16x16x32_bf16(af0, bg, accg[0], 0, 0, 0);
      accg[1] = __builtin_amdgcn_mfma_f32_16x16x32_bf16(af1, bg, accg[1], 0, 0, 0);
      accu[0] = __builtin_amdgcn_mfma_f32_16x16x32_bf16(af0, bu, accu[0], 0, 0, 0);
      accu[1] = __builtin_amdgcn_mfma_f32_16x16x32_bf16(af1, bu, accu[1], 0, 0, 0);
    }
  }

  // epilogue: h = silu(g)*u -> blocked layout (contiguous 4-KB per block)
#pragma unroll
  for (int i = 0; i < 2; i++)
#pragma unroll
    for (int g = 0; g < 4; g++) {
      int rloc = wv * 32 + i * 16 + quad * 4 + g;
      int slot = mt * 128 + rloc;
      if (slot < cnt) {
        float gv = accg[i][g], uv = accu[i][g];
        float h = gv / (1.f + __expf(-gv)) * uv;
        obase[(size_t)slot * 16 + l16] = f2bf(h);
      }
    }
}

// ---- down expert: out[tok] += pw * (hbuf_e @ Wd_e^T), M=128 N=32 K=1024 ----
__global__ __launch_bounds__(256) void down_expert_kernel(
    const u16* __restrict__ hbufB, const float* __restrict__ Wd,
    float* __restrict__ out, const int* __restrict__ ptok,
    const float* __restrict__ pw, const int* __restrict__ counts) {
  __shared__ __align__(16) u16 As[4 * 128 * 16];  // [j'][slot][16] = 16 KB
  __shared__ __align__(16) float Bsf[32 * 64];    // 8 KB

  int b = blockIdx.x;
  int t = threadIdx.x;
  int e = b & 7, nt = (b >> 3) & 63, mt = b >> 9;
  int cnt = counts[e];
  if (mt * 128 >= cnt) return;

  int lane = t & 63, wv = t >> 6;
  int quad = lane >> 4, l16 = lane & 15;

  const u16* hb = hbufB + (size_t)e * 524288;  // e*64*8192

  // A: per iter needs j = 4kt..4kt+3 (hbuf is [j][512][16]); wave wv stages
  // j' = wv, 4 chunks i: slots i*32 + (l>>1), 16-B half (l&1).
  const u16* aptr[4];
  u16* alds[4];
#pragma unroll
  for (int i = 0; i < 4; i++) {
    aptr[i] = hb + (size_t)wv * 8192 + (size_t)(mt * 128 + i * 32 + (lane >> 1)) * 16
              + (lane & 1) * 8;
    alds[i] = &As[wv * 2048 + i * 512];
  }
  // B: rows nt*32..+32 of Wd_e, 8 chunks of 4 rows; wave wv chunks 2wv,2wv+1
  const float* bptr[2];
  float* blds[2];
#pragma unroll
  for (int i = 0; i < 2; i++) {
    int c = 2 * wv + i;
    int rloc = 4 * c + (lane >> 4);
    bptr[i] = Wd + (size_t)(e * 2048 + nt * 32 + rloc) * 1024 + (lane & 15) * 4;
    blds[i] = &Bsf[c * 256];
  }

  f32x4 acc[2][2] = {};

  for (int kt = 0; kt < 16; kt++) {
    __syncthreads();
#pragma unroll
    for (int i = 0; i < 4; i++) gld16(aptr[i] + (size_t)kt * 32768, alds[i]);
#pragma unroll
    for (int i = 0; i < 2; i++) gld16(bptr[i] + kt * 64, blds[i]);
    __syncthreads();
#pragma unroll
    for (int k2 = 0; k2 < 2; k2++) {
      // A frag: k = k2*32+quad*8+jj -> j' = k2*2+(quad>>1), elem (quad&1)*8
      int jsec = (k2 * 2 + (quad >> 1)) * 2048 + (quad & 1) * 8;
      bf16x8 af0 = ldfrag(&As[jsec + (wv * 32 + l16) * 16]);
      bf16x8 af1 = ldfrag(&As[jsec + (wv * 32 + 16 + l16) * 16]);
      bf16x8 b0 = cvt8(&Bsf[l16 * 64 + k2 * 32 + quad * 8]);
      bf16x8 b1 = cvt8(&Bsf[(16 + l16) * 64 + k2 * 32 + quad * 8]);
      acc[0][0] = __builtin_amdgcn_mfma_f32_16x16x32_bf16(af0, b0, acc[0][0], 0, 0, 0);
      acc[0][1] = __builtin_amdgcn_mfma_f32_16x16x32_bf16(af0, b1, acc[0][1], 0, 0, 0);
      acc[1][0] = __builtin_amdgcn_mfma_f32_16x16x32_bf16(af1, b0, acc[1][0], 0, 0, 0);
      acc[1][1] = __builtin_amdgcn_mfma_f32_16x16x32_bf16(af1, b1, acc[1][1], 0, 0, 0);
    }
  }

#pragma unroll
  for (int i = 0; i < 2; i++)
#pragma unroll
    for (int jf = 0; jf < 2; jf++)
#pragma unroll
      for (int g = 0; g < 4; g++) {
        int sl = mt * 128 + wv * 32 + i * 16 + quad * 4 + g;
        if (sl < cnt) {
          int tok = ptok[(e << 9) + sl];
          int col = nt * 32 + jf * 16 + l16;
          atomicAdd(&out[(size_t)tok * 2048 + col], pw[(e << 9) + sl] * acc[i][jf][g]);
        }
      }
}

// ---- down shared: out[row] = sgate[row] * (hs @ SWd^T), M=128 N=16 K=2048 ----
__global__ __launch_bounds__(256) void down_shared_kernel(
    const u16* __restrict__ hsB, const float* __restrict__ SWd,
    float* __restrict__ out, const float* __restrict__ sgate) {
  __shared__ __align__(16) u16 As[4 * 128 * 16];  // 16 KB
  __shared__ __align__(16) float Bsf[16 * 64];    // 4 KB

  int bs = blockIdx.x;
  int t = threadIdx.x;
  // same-nt blocks pinned to one XCD so SWd rows fetch once
  int xcd = bs & 7, mt = (bs >> 3) & 3, nt = (bs >> 5) * 8 + xcd;

  int lane = t & 63, wv = t >> 6;
  int quad = lane >> 4, l16 = lane & 15;

  const u16* aptr[4];
  u16* alds[4];
#pragma unroll
  for (int i = 0; i < 4; i++) {
    aptr[i] = hsB + (size_t)wv * 8192 + (size_t)(mt * 128 + i * 32 + (lane >> 1)) * 16
              + (lane & 1) * 8;
    alds[i] = &As[wv * 2048 + i * 512];
  }
  // B: rows nt*16..+16, 4 chunks of 4 rows; wave wv stages chunk wv
  const float* bptr = SWd + (size_t)(nt * 16 + 4 * wv + (lane >> 4)) * 2048
                      + (lane & 15) * 4;
  float* blds = &Bsf[wv * 256];

  f32x4 acc[2] = {};

  for (int kt = 0; kt < 32; kt++) {
    __syncthreads();
#pragma unroll
    for (int i = 0; i < 4; i++) gld16(aptr[i] + (size_t)kt * 32768, alds[i]);
    gld16(bptr + kt * 64, blds);
    __syncthreads();
#pragma unroll
    for (int k2 = 0; k2 < 2; k2++) {
      int jsec = (k2 * 2 + (quad >> 1)) * 2048 + (quad & 1) * 8;
      bf16x8 af0 = ldfrag(&As[jsec + (wv * 32 + l16) * 16]);
      bf16x8 af1 = ldfrag(&As[jsec + (wv * 32 + 16 + l16) * 16]);
      bf16x8 bb = cvt8(&Bsf[l16 * 64 + k2 * 32 + quad * 8]);
      acc[0] = __builtin_amdgcn_mfma_f32_16x16x32_bf16(af0, bb, acc[0], 0, 0, 0);
      acc[1] = __builtin_amdgcn_mfma_f32_16x16x32_bf16(af1, bb, acc[1], 0, 0, 0);
    }
  }

#pragma unroll
  for (int i = 0; i < 2; i++)
#pragma unroll
    for (int g = 0; g < 4; g++) {
      int row = mt * 128 + wv * 32 + i * 16 + quad * 4 + g;
      out[(size_t)row * 2048 + nt * 16 + l16] = sgate[row] * acc[i][g];
    }
}

extern "C" void kernel_launch(void* const* d_in, const int* in_sizes, int n_in,
                              void* d_out, int out_size, void* d_ws, size_t ws_size,
                              hipStream_t stream) {
  const float* x = (const float*)d_in[0];
  const float* gate_w = (const float*)d_in[1];
  const float* w_gate = (const float*)d_in[2];
  const float* w_up = (const float*)d_in[3];
  const float* w_down = (const float*)d_in[4];
  const float* sh_gate = (const float*)d_in[5];
  const float* sh_up = (const float*)d_in[6];
  const float* sh_down = (const float*)d_in[7];
  const float* se_gate_w = (const float*)d_in[8];
  float* out = (float*)d_out;

  char* ws = (char*)d_ws;
  int* counts = (int*)(ws + 0);                       // 32 B
  int* ptok = (int*)(ws + 1024);                      // 16 KB
  float* pw = (float*)(ws + 1024 + 16384);            // 16 KB
  float* sg = (float*)(ws + 1024 + 32768);            // 2 KB
  u16* xb = (u16*)(ws + 65536);                       // 2 MB
  u16* hbufB = (u16*)(ws + 65536 + (2u << 20));       // [e][j][512][16] = 8 MB
  u16* hsB = (u16*)(ws + 65536 + (10u << 20));        // [j][512][16] = 2 MB

  hipMemsetAsync(counts, 0, 32, stream);
  routing_kernel<<<512, 64, 0, stream>>>(x, gate_w, se_gate_w, counts, ptok, pw, sg);
  prep_kernel<<<128, 256, 0, stream>>>(x, xb);
  // gateup: expert 8e*64j*4mt = 2048 (live ~512) + shared 512
  gateup_kernel<<<2560, 256, 0, stream>>>(xb, w_gate, w_up, sh_gate, sh_up,
                                          hbufB, hsB, ptok, counts);
  // shared down first (plain store covers every out element) ...
  down_shared_kernel<<<512, 256, 0, stream>>>(hsB, sh_down, out, sg);
  // ... then expert down atomicAdds on top
  down_expert_kernel<<<2048, 256, 0, stream>>>(hbufB, w_down, out, ptok, pw, counts);
}